// Round 1
// baseline (112126.685 us; speedup 1.0000x reference)
//
#include <hip/hip_runtime.h>
#include <cstdint>
#include <cstddef>

#define B_  64
#define T_  512
#define D_  512
#define H0_ 1024
#define H1_ 512

__device__ __forceinline__ float sigmf(float x) { return 1.0f / (1.0f + __expf(-x)); }

// ---------------------------------------------------------------------------
// mask[b,t] = any(inputs[b,t,:] != 0)   — one wave (64 lanes) per row
// ---------------------------------------------------------------------------
__global__ void mask_kernel(const float* __restrict__ x, unsigned char* __restrict__ mask) {
    int row  = blockIdx.x * 4 + (threadIdx.x >> 6);   // 4 waves per block
    int lane = threadIdx.x & 63;
    const float4* p = reinterpret_cast<const float4*>(x + (size_t)row * D_) + lane * 2;
    float4 a = p[0], b = p[1];
    bool nz = (a.x != 0.f) | (a.y != 0.f) | (a.z != 0.f) | (a.w != 0.f)
            | (b.x != 0.f) | (b.y != 0.f) | (b.z != 0.f) | (b.w != 0.f);
    int m = __any(nz);
    if (lane == 0) mask[row] = m ? 1 : 0;
}

__global__ void zero_kernel(float* __restrict__ p, int n) {
    int i = blockIdx.x * blockDim.x + threadIdx.x;
    if (i < n) p[i] = 0.f;
}

// ---------------------------------------------------------------------------
// One LSTM timestep. z = [x_t, h_prev] @ [W;U] + bias, then gates.
// Block tile: 32 batches x 8 hidden units (= 32 z-columns across 4 gates).
// Grid: (HD/8) * 2 blocks, 256 threads.
// hr = h(t-1) read buffer, hw = h(t) write buffer (double buffered).
// c is owner-only (read+write by the same block) -> single buffer.
// ---------------------------------------------------------------------------
template<int DIN, int HD>
__global__ __launch_bounds__(256)
void lstm_step(const float* __restrict__ xbase, int xstride,
               const float* __restrict__ W,      // [DIN, 4*HD]
               const float* __restrict__ U,      // [HD, 4*HD]
               const float* __restrict__ bias,   // [4*HD]
               const unsigned char* __restrict__ mask, int t,
               const float* __restrict__ hr, float* __restrict__ hw,
               float* __restrict__ c, float* __restrict__ out)
{
    constexpr int K = DIN + HD;       // 1536 for both layers
    __shared__ float As[32][36];      // [k][m]  (transposed A tile, padded)
    __shared__ float Bs[32][34];      // [k][n]
    __shared__ float Zs[32][33];      // [m][n]  z tile for gate phase

    const int tid = threadIdx.x;
    const int bb0 = (blockIdx.x & 1) * 32;        // batch offset (0 or 32)
    const int k0  = (blockIdx.x >> 1) * 8;        // hidden-unit offset

    // compute mapping: thread owns 2m x 2n outputs
    const int tm = tid & 15;   const int m0 = tm * 2;
    const int tn = tid >> 4;   const int n0 = tn * 2;

    // A-staging mapping: row m = tid&31, k-quad = (tid>>5)*4
    const int am = tid & 31;
    const int ak = (tid >> 5) * 4;

    float acc00, acc01, acc10, acc11;
    {
        int g0 = n0 >> 3, j0 = n0 & 7;
        int n1 = n0 + 1; int g1 = n1 >> 3, j1 = n1 & 7;
        acc00 = bias[g0 * HD + k0 + j0];
        acc01 = bias[g1 * HD + k0 + j1];
        acc10 = acc00;
        acc11 = acc01;
    }

    for (int kt = 0; kt < K; kt += 32) {
        // ---- stage A tile (transposed): As[k][m] = A[bb0+am][kt+k]
        {
            int kk = kt + ak;
            const float* asrc;
            if (kk < DIN) asrc = xbase + (size_t)(bb0 + am) * xstride + kk;
            else          asrc = hr + (size_t)(bb0 + am) * HD + (kk - DIN);
            float4 av = *reinterpret_cast<const float4*>(asrc);
            As[ak + 0][am] = av.x;
            As[ak + 1][am] = av.y;
            As[ak + 2][am] = av.z;
            As[ak + 3][am] = av.w;
        }
        // ---- stage B tile: Bs[k][n] = B[kt+k][col(n)], col(n)=(n>>3)*HD + k0 + (n&7)
        #pragma unroll
        for (int i = 0; i < 4; ++i) {
            int e = tid + i * 256;
            int k = e >> 5, n = e & 31;
            int row = kt + k;
            int col = (n >> 3) * HD + k0 + (n & 7);
            float v = (row < DIN) ? W[(size_t)row * (4 * HD) + col]
                                  : U[(size_t)(row - DIN) * (4 * HD) + col];
            Bs[k][n] = v;
        }
        __syncthreads();
        #pragma unroll
        for (int k = 0; k < 32; ++k) {
            float2 a  = *reinterpret_cast<const float2*>(&As[k][m0]);
            float2 bv = *reinterpret_cast<const float2*>(&Bs[k][n0]);
            acc00 = fmaf(a.x, bv.x, acc00);
            acc01 = fmaf(a.x, bv.y, acc01);
            acc10 = fmaf(a.y, bv.x, acc10);
            acc11 = fmaf(a.y, bv.y, acc11);
        }
        __syncthreads();
    }

    // ---- write z tile to LDS for the gate phase
    Zs[m0 + 0][n0 + 0] = acc00;
    Zs[m0 + 0][n0 + 1] = acc01;
    Zs[m0 + 1][n0 + 0] = acc10;
    Zs[m0 + 1][n0 + 1] = acc11;
    __syncthreads();

    // ---- gates: thread handles (m = tid&31, j = tid>>5)
    {
        int m = tid & 31, j = tid >> 5;
        int b = bb0 + m;
        int kg = k0 + j;
        float zi = Zs[m][j];
        float zf = Zs[m][8 + j];
        float zg = Zs[m][16 + j];
        float zo = Zs[m][24 + j];
        float ig = sigmf(zi), fg = sigmf(zf), gg = tanhf(zg), og = sigmf(zo);
        size_t idx = (size_t)b * HD + kg;
        float c_old = c[idx];
        float c_new = fg * c_old + ig * gg;
        float h_new = og * tanhf(c_new);
        if (!mask[b * T_ + t]) { c_new = c_old; h_new = hr[idx]; }
        c[idx]  = c_new;
        hw[idx] = h_new;
        if (out) out[((size_t)b * T_ + t) * HD + kg] = h_new;
    }
}

// ---------------------------------------------------------------------------
extern "C" void kernel_launch(void* const* d_in, const int* in_sizes, int n_in,
                              void* d_out, int out_size, void* d_ws, size_t ws_size,
                              hipStream_t stream)
{
    const float* inputs = (const float*)d_in[0];
    const float* W0     = (const float*)d_in[1];
    const float* U0     = (const float*)d_in[2];
    const float* bias0  = (const float*)d_in[3];
    const float* W1     = (const float*)d_in[4];
    const float* U1     = (const float*)d_in[5];
    const float* bias1  = (const float*)d_in[6];
    float* out = (float*)d_out;

    // workspace layout (floats): h0[2][64*1024] c0[64*1024] h1[2][64*512] c1[64*512], then mask bytes
    float* h0 = (float*)d_ws;
    float* c0 = h0 + 2 * B_ * H0_;
    float* h1 = c0 + B_ * H0_;
    float* c1 = h1 + 2 * B_ * H1_;
    unsigned char* mask = (unsigned char*)(c1 + B_ * H1_);

    int zn = 2 * B_ * H0_ + B_ * H0_ + 2 * B_ * H1_ + B_ * H1_;
    zero_kernel<<<(zn + 255) / 256, 256, 0, stream>>>(h0, zn);
    mask_kernel<<<(B_ * T_) / 4, 256, 0, stream>>>(inputs, mask);

    for (int t = 0; t < T_; ++t) {
        const float* h0r = h0 + (size_t)(t & 1) * B_ * H0_;
        float*       h0w = h0 + (size_t)((t + 1) & 1) * B_ * H0_;
        const float* h1r = h1 + (size_t)(t & 1) * B_ * H1_;
        float*       h1w = h1 + (size_t)((t + 1) & 1) * B_ * H1_;

        // layer 0: x = inputs[:, t, :], DIN=512, HD=1024, 256 blocks
        lstm_step<D_, H0_><<<256, 256, 0, stream>>>(
            inputs + (size_t)t * D_, T_ * D_,
            W0, U0, bias0, mask, t, h0r, h0w, c0, nullptr);

        // layer 1: x = h0(t) (just written), DIN=1024, HD=512, 128 blocks
        lstm_step<H0_, H1_><<<128, 256, 0, stream>>>(
            h0w, H0_,
            W1, U1, bias1, mask, t, h1r, h1w, c1, out);
    }
}

// Round 2
// 20220.502 us; speedup vs baseline: 5.5452x; 5.5452x over previous
//
#include <hip/hip_runtime.h>
#include <hip/hip_bf16.h>
#include <hip/hip_cooperative_groups.h>
#include <cstdint>
#include <cstddef>

namespace cg = cooperative_groups;

#define B_   64
#define T_   512
#define D_   512
#define H0_  1024
#define H1_  512
#define KTOT 1536
#define NBLK 256
#define NL0  128

typedef __attribute__((ext_vector_type(8))) short bf16x8;
typedef __attribute__((ext_vector_type(4))) float f32x4;

#define LDS_BYTES 132096     // 96KB weight frags + 33KB padded z-partials
#define ZP_OFF    98304

__device__ __forceinline__ float sigmf(float x) { return 1.0f / (1.0f + __expf(-x)); }

// ---------------------------------------------------------------------------
// mask[b,t] = any(inputs[b,t,:] != 0) — one wave per row
// ---------------------------------------------------------------------------
__global__ void mask_kernel(const float* __restrict__ x, unsigned char* __restrict__ mask) {
    int row  = blockIdx.x * 4 + (threadIdx.x >> 6);
    int lane = threadIdx.x & 63;
    const float4* p = reinterpret_cast<const float4*>(x + (size_t)row * D_) + lane * 2;
    float4 a = p[0], b = p[1];
    bool nz = (a.x != 0.f) | (a.y != 0.f) | (a.z != 0.f) | (a.w != 0.f)
            | (b.x != 0.f) | (b.y != 0.f) | (b.z != 0.f) | (b.w != 0.f);
    int m = __any(nz);
    if (lane == 0) mask[row] = m ? 1 : 0;
}

// ---------------------------------------------------------------------------
// inputs [B][T][D] f32 -> xbf [T][B][D] bf16
// ---------------------------------------------------------------------------
__global__ void xbf_kernel(const float* __restrict__ in, __hip_bfloat16* __restrict__ xbf) {
    int i  = blockIdx.x * 256 + threadIdx.x;     // octet index
    int d8 = i & 63;                              // D/8 = 64
    int row = i >> 6;                             // b*T + t
    int b = row >> 9, t = row & 511;
    const float* src = in + (size_t)row * D_ + d8 * 8;
    __hip_bfloat16 o[8];
    #pragma unroll
    for (int j = 0; j < 8; ++j) o[j] = __float2bfloat16(src[j]);
    *reinterpret_cast<bf16x8*>(xbf + ((size_t)t * B_ + b) * D_ + d8 * 8) =
        *reinterpret_cast<bf16x8*>(o);
}

// ---------------------------------------------------------------------------
// Persistent per-layer loop. Block owns UPB hidden units (4*UPB z-columns).
// K=1536 split across 4 waves (12 k-chunks of 32 each); partials reduced in LDS.
// A-source: k < S0 from a0 (row stride ST0), else a1 (row stride ST1).
// ---------------------------------------------------------------------------
template<bool ISL0, int S0, int ST0, int ST1, int NF, int HD, int UPB, int UPT>
__device__ void run_layer(unsigned char* smem, cg::grid_group& grid,
    const float* __restrict__ W, const float* __restrict__ U, const float* __restrict__ bias,
    const __hip_bfloat16* __restrict__ xbf,
    __hip_bfloat16* h0buf, __hip_bfloat16* h1buf,
    const unsigned char* __restrict__ mask,
    float* __restrict__ out, int ubase)
{
    const int tid = threadIdx.x;
    __hip_bfloat16* wlds = (__hip_bfloat16*)smem;
    float* zp = (float*)(smem + ZP_OFF);
    constexpr int ZROW = NF * 16 + 1;            // pad to kill bank conflicts

    // ---- one-time: fill LDS weight slice, pre-swizzled into MFMA B-fragment order
    for (int e = tid; e < 48 * NF * 64; e += 256) {
        int ln  = e & 63;
        int nf  = (e >> 6) % NF;
        int ksg = e / (64 * NF);
        int nn  = nf * 16 + (ln & 15);
        int col = (nn / UPB) * HD + ubase + (nn % UPB);   // gate-major columns
        int kb  = ksg * 32 + (ln >> 4) * 8;
        __hip_bfloat16* dst = wlds + ((size_t)(ksg * NF + nf) * 64 + ln) * 8;
        #pragma unroll
        for (int j = 0; j < 8; ++j) {
            int k = kb + j;
            float v = (k < S0) ? W[(size_t)k * (4 * HD) + col]
                               : U[(size_t)(k - S0) * (4 * HD) + col];
            dst[j] = __float2bfloat16(v);
        }
    }

    // ---- per-thread recurrent state: batch b, UPT consecutive units
    const int b  = tid >> 2;
    const int qq = tid & 3;
    float hreg[UPT], creg[UPT], breg[UPT * 4];
    #pragma unroll
    for (int i = 0; i < UPT; ++i) {
        hreg[i] = 0.f; creg[i] = 0.f;
        #pragma unroll
        for (int g = 0; g < 4; ++g)
            breg[i * 4 + g] = bias[g * HD + ubase + qq * UPT + i];
    }
    __syncthreads();

    const int w = tid >> 6, lane = tid & 63;
    const int mr = lane & 15, kgrp = lane >> 4;

    #pragma unroll 1
    for (int p = 0; p <= T_; ++p) {
        const int t = ISL0 ? p : (p - 1);
        const bool active = ISL0 ? (p < T_) : (p >= 1);
        if (active) {
            const __hip_bfloat16* a0;
            const __hip_bfloat16* a1;
            __hip_bfloat16* hw;
            if (ISL0) {
                a0 = xbf + (size_t)t * B_ * D_;
                a1 = h0buf + ((t + 1) & 1) * (B_ * H0_);
                hw = h0buf + (t & 1) * (B_ * H0_);
            } else {
                a0 = h0buf + (t & 1) * (B_ * H0_);
                a1 = h1buf + ((t + 1) & 1) * (B_ * H1_);
                hw = h1buf + (t & 1) * (B_ * H1_);
            }

            // ---- MFMA partial GEMM over this wave's k-slice
            f32x4 acc[4][NF];
            #pragma unroll
            for (int m = 0; m < 4; ++m)
                #pragma unroll
                for (int nf = 0; nf < NF; ++nf) {
                    f32x4 z = {0.f, 0.f, 0.f, 0.f};
                    acc[m][nf] = z;
                }
            #pragma unroll
            for (int ks = 0; ks < 12; ++ks) {
                const int k0 = w * 384 + ks * 32;
                const __hip_bfloat16* src;
                int st;
                if (k0 < S0) { src = a0 + k0 + kgrp * 8;        st = ST0; }
                else         { src = a1 + (k0 - S0) + kgrp * 8; st = ST1; }
                bf16x8 bf[NF];
                #pragma unroll
                for (int nf = 0; nf < NF; ++nf)
                    bf[nf] = *reinterpret_cast<const bf16x8*>(
                        wlds + ((size_t)((w * 12 + ks) * NF + nf) * 64 + lane) * 8);
                #pragma unroll
                for (int m = 0; m < 4; ++m) {
                    const bf16x8 af = *reinterpret_cast<const bf16x8*>(
                        src + (size_t)(m * 16 + mr) * st);
                    #pragma unroll
                    for (int nf = 0; nf < NF; ++nf)
                        acc[m][nf] = __builtin_amdgcn_mfma_f32_16x16x32_bf16(
                            af, bf[nf], acc[m][nf], 0, 0, 0);
                }
            }
            // ---- dump partials (C layout: row=(lane>>4)*4+r, col=lane&15)
            #pragma unroll
            for (int m = 0; m < 4; ++m)
                #pragma unroll
                for (int nf = 0; nf < NF; ++nf)
                    #pragma unroll
                    for (int r = 0; r < 4; ++r)
                        zp[(w * 64 + m * 16 + kgrp * 4 + r) * ZROW + nf * 16 + mr] =
                            acc[m][nf][r];
            __syncthreads();

            // ---- reduce partials + gates + state update
            const bool msk = mask[b * T_ + t] != 0;
            #pragma unroll
            for (int i = 0; i < UPT; ++i) {
                const int ul = qq * UPT + i;
                float z[4];
                #pragma unroll
                for (int g = 0; g < 4; ++g) {
                    float s = breg[i * 4 + g];
                    #pragma unroll
                    for (int wv = 0; wv < 4; ++wv)
                        s += zp[(wv * 64 + b) * ZROW + g * UPB + ul];
                    z[g] = s;
                }
                float ig = sigmf(z[0]), fg = sigmf(z[1]);
                float gg = tanhf(z[2]), og = sigmf(z[3]);
                float cn = fg * creg[i] + ig * gg;
                float hn = og * tanhf(cn);
                if (msk) { creg[i] = cn; hreg[i] = hn; }
                hw[(size_t)b * HD + ubase + ul] = __float2bfloat16(hreg[i]);
                if (!ISL0) out[((size_t)b * T_ + t) * HD + ubase + ul] = hreg[i];
            }
        }
        grid.sync();   // also orders zp reuse & h-buffer visibility across XCDs
    }
}

__global__ __launch_bounds__(256, 1)
void lstm_persistent(const __hip_bfloat16* __restrict__ xbf,
    const float* __restrict__ W0, const float* __restrict__ U0, const float* __restrict__ b0,
    const float* __restrict__ W1, const float* __restrict__ U1, const float* __restrict__ b1,
    const unsigned char* __restrict__ mask,
    __hip_bfloat16* h0buf, __hip_bfloat16* h1buf, float* __restrict__ out)
{
    __shared__ __align__(16) unsigned char smem[LDS_BYTES];
    cg::grid_group grid = cg::this_grid();
    const int bid = blockIdx.x;
    if (bid < NL0) {
        run_layer<true, 512, 512, 1024, 2, 1024, 8, 2>(
            smem, grid, W0, U0, b0, xbf, h0buf, h1buf, mask, nullptr, bid * 8);
    } else {
        run_layer<false, 1024, 1024, 512, 1, 512, 4, 1>(
            smem, grid, W1, U1, b1, xbf, h0buf, h1buf, mask, out, (bid - NL0) * 4);
    }
}

// ---------------------------------------------------------------------------
extern "C" void kernel_launch(void* const* d_in, const int* in_sizes, int n_in,
                              void* d_out, int out_size, void* d_ws, size_t ws_size,
                              hipStream_t stream)
{
    const float* inputs = (const float*)d_in[0];
    const float* W0     = (const float*)d_in[1];
    const float* U0     = (const float*)d_in[2];
    const float* b0     = (const float*)d_in[3];
    const float* W1     = (const float*)d_in[4];
    const float* U1     = (const float*)d_in[5];
    const float* b1     = (const float*)d_in[6];
    float* out = (float*)d_out;

    // ws layout: xbf [T][B][D] bf16, h0buf[2][B][H0] bf16, h1buf[2][B][H1] bf16, mask
    __hip_bfloat16* xbf   = (__hip_bfloat16*)d_ws;
    __hip_bfloat16* h0buf = xbf + (size_t)T_ * B_ * D_;
    __hip_bfloat16* h1buf = h0buf + 2 * B_ * H0_;
    unsigned char*  mask  = (unsigned char*)(h1buf + 2 * B_ * H1_);

    hipMemsetAsync(h0buf, 0, (size_t)(2 * B_ * H0_ + 2 * B_ * H1_) * sizeof(__hip_bfloat16), stream);
    mask_kernel<<<(B_ * T_) / 4, 256, 0, stream>>>(inputs, mask);
    xbf_kernel<<<(B_ * T_ * D_ / 8) / 256, 256, 0, stream>>>(inputs, xbf);

    const __hip_bfloat16* xbf_c = xbf;
    const unsigned char* mask_c = mask;
    void* args[] = {
        (void*)&xbf_c, (void*)&W0, (void*)&U0, (void*)&b0,
        (void*)&W1, (void*)&U1, (void*)&b1,
        (void*)&mask_c, (void*)&h0buf, (void*)&h1buf, (void*)&out
    };
    hipLaunchCooperativeKernel((void*)lstm_persistent, dim3(NBLK), dim3(256),
                               args, 0, stream);
}

// Round 3
// 14365.839 us; speedup vs baseline: 7.8051x; 1.4075x over previous
//
#include <hip/hip_runtime.h>
#include <hip/hip_bf16.h>
#include <hip/hip_cooperative_groups.h>
#include <cstdint>
#include <cstddef>

#define B_   64
#define T_   512
#define D_   512
#define H0_  1024
#define H1_  512
#define NBLK 256
#define NL0  128

typedef __attribute__((ext_vector_type(8))) short bf16x8;
typedef __attribute__((ext_vector_type(4))) float f32x4;

#define LDS_BYTES 135168     // 96KB weight frags + 36KB padded z-partials
#define ZP_OFF    98304

__device__ __forceinline__ float sigmf(float x) { return 1.0f / (1.0f + __expf(-x)); }

// ---------------------------------------------------------------------------
// Custom grid barrier: monotonic counter + release flag, agent scope.
// ---------------------------------------------------------------------------
__device__ __forceinline__ void bar_wait(int* flg, int p) {
    if (p > 0) {
        if (threadIdx.x == 0) {
            while (__hip_atomic_load(flg, __ATOMIC_ACQUIRE, __HIP_MEMORY_SCOPE_AGENT) < p)
                __builtin_amdgcn_s_sleep(2);
        }
        __syncthreads();
    }
}

__device__ __forceinline__ void bar_arrive(int* cnt, int* flg, int p) {
    __syncthreads();                 // drains each wave's stores (vmcnt0 before s_barrier)
    if (threadIdx.x == 0) {
        __threadfence();             // agent-scope release: cross-XCD visibility of h writes
        int v = __hip_atomic_fetch_add(cnt, 1, __ATOMIC_ACQ_REL, __HIP_MEMORY_SCOPE_AGENT);
        if (v == (p + 1) * NBLK - 1)
            __hip_atomic_store(flg, p + 1, __ATOMIC_RELEASE, __HIP_MEMORY_SCOPE_AGENT);
    }
}

// ---------------------------------------------------------------------------
// mask[b,t] = any(inputs[b,t,:] != 0) — one wave per row
// ---------------------------------------------------------------------------
__global__ void mask_kernel(const float* __restrict__ x, unsigned char* __restrict__ mask) {
    int row  = blockIdx.x * 4 + (threadIdx.x >> 6);
    int lane = threadIdx.x & 63;
    const float4* p = reinterpret_cast<const float4*>(x + (size_t)row * D_) + lane * 2;
    float4 a = p[0], b = p[1];
    bool nz = (a.x != 0.f) | (a.y != 0.f) | (a.z != 0.f) | (a.w != 0.f)
            | (b.x != 0.f) | (b.y != 0.f) | (b.z != 0.f) | (b.w != 0.f);
    int m = __any(nz);
    if (lane == 0) mask[row] = m ? 1 : 0;
}

// ---------------------------------------------------------------------------
// inputs [B][T][D] f32 -> xbf [T][B][D] bf16
// ---------------------------------------------------------------------------
__global__ void xbf_kernel(const float* __restrict__ in, __hip_bfloat16* __restrict__ xbf) {
    int i  = blockIdx.x * 256 + threadIdx.x;     // octet index
    int d8 = i & 63;                              // D/8 = 64
    int row = i >> 6;                             // b*T + t
    int b = row >> 9, t = row & 511;
    const float* src = in + (size_t)row * D_ + d8 * 8;
    __hip_bfloat16 o[8];
    #pragma unroll
    for (int j = 0; j < 8; ++j) o[j] = __float2bfloat16(src[j]);
    *reinterpret_cast<bf16x8*>(xbf + ((size_t)t * B_ + b) * D_ + d8 * 8) =
        *reinterpret_cast<bf16x8*>(o);
}

// ---------------------------------------------------------------------------
// Persistent per-layer loop. Block owns UPB hidden units (4*UPB z-columns).
// K=1536 over 4 waves. L0 k-chunk map: wave w gets 4 x-chunks (cid=w*4+c,
// k<512, computed BEFORE the barrier wait) + 8 h-chunks (cid=16+w*8+c).
// L1: contiguous cid=w*12+c (all dynamic).
// ---------------------------------------------------------------------------
template<bool ISL0, int S0, int ST0, int ST1, int NF, int HD, int UPB, int UPT>
__device__ void run_layer(unsigned char* smem,
    const float* __restrict__ W, const float* __restrict__ U, const float* __restrict__ bias,
    const __hip_bfloat16* __restrict__ xbf,
    __hip_bfloat16* h0buf, __hip_bfloat16* h1buf,
    const unsigned char* __restrict__ mask,
    float* __restrict__ out, int ubase, int* bcnt, int* bflg)
{
    const int tid = threadIdx.x;
    __hip_bfloat16* wlds = (__hip_bfloat16*)smem;
    float* zp = (float*)(smem + ZP_OFF);
    constexpr int ZROW = (NF == 2) ? 36 : 20;    // 4*ZROW % 32 == 16 -> 2 lanes/bank (free)

    // ---- one-time: fill LDS weight slice, pre-swizzled into MFMA B-fragment order
    for (int e = tid; e < 48 * NF * 64; e += 256) {
        int ln  = e & 63;
        int nf  = (e >> 6) % NF;
        int cid = e / (64 * NF);
        int nn  = nf * 16 + (ln & 15);
        int col = (nn / UPB) * HD + ubase + (nn % UPB);   // gate-major columns
        int kb  = cid * 32 + (ln >> 4) * 8;
        __hip_bfloat16* dst = wlds + ((size_t)(cid * NF + nf) * 64 + ln) * 8;
        #pragma unroll
        for (int j = 0; j < 8; ++j) {
            int k = kb + j;
            float v = (k < S0) ? W[(size_t)k * (4 * HD) + col]
                               : U[(size_t)(k - S0) * (4 * HD) + col];
            dst[j] = __float2bfloat16(v);
        }
    }

    // ---- per-thread recurrent state: batch b = tid>>2, UPT consecutive units
    const int b  = tid >> 2;
    const int qq = tid & 3;
    float hreg[UPT], creg[UPT], breg[UPT * 4];
    #pragma unroll
    for (int i = 0; i < UPT; ++i) {
        hreg[i] = 0.f; creg[i] = 0.f;
        #pragma unroll
        for (int g = 0; g < 4; ++g)
            breg[i * 4 + g] = bias[g * HD + ubase + qq * UPT + i];
    }
    __syncthreads();

    const int w = tid >> 6, lane = tid & 63;
    const int mr = lane & 15, kgrp = lane >> 4;

    #pragma unroll 1
    for (int p = 0; p <= T_; ++p) {
        const int t = ISL0 ? p : (p - 1);
        const bool active = ISL0 ? (p < T_) : (p >= 1);

        f32x4 acc[4][NF];
        if (active) {
            #pragma unroll
            for (int m = 0; m < 4; ++m)
                #pragma unroll
                for (int nf = 0; nf < NF; ++nf) {
                    f32x4 z = {0.f, 0.f, 0.f, 0.f};
                    acc[m][nf] = z;
                }
        }

        // ---- PRE: x-only chunks (L0), independent of the barrier
        if (ISL0 && active) {
            const __hip_bfloat16* a0 = xbf + (size_t)t * B_ * D_;
            #pragma unroll
            for (int c = 0; c < 4; ++c) {
                const int cid = w * 4 + c;
                const __hip_bfloat16* src = a0 + cid * 32 + kgrp * 8;
                bf16x8 bf[NF];
                #pragma unroll
                for (int nf = 0; nf < NF; ++nf)
                    bf[nf] = *reinterpret_cast<const bf16x8*>(
                        wlds + ((size_t)(cid * NF + nf) * 64 + lane) * 8);
                #pragma unroll
                for (int m = 0; m < 4; ++m) {
                    const bf16x8 af = *reinterpret_cast<const bf16x8*>(
                        src + (size_t)(m * 16 + mr) * ST0);
                    #pragma unroll
                    for (int nf = 0; nf < NF; ++nf)
                        acc[m][nf] = __builtin_amdgcn_mfma_f32_16x16x32_bf16(
                            af, bf[nf], acc[m][nf], 0, 0, 0);
                }
            }
        }

        // ---- wait for h(t-1) from all blocks
        bar_wait(bflg, p);

        if (active) {
            const __hip_bfloat16* a0;
            const __hip_bfloat16* a1;
            __hip_bfloat16* hw;
            if (ISL0) {
                a0 = nullptr;  // x handled in PRE
                a1 = h0buf + ((t + 1) & 1) * (B_ * H0_);
                hw = h0buf + (t & 1) * (B_ * H0_);
            } else {
                a0 = h0buf + (t & 1) * (B_ * H0_);
                a1 = h1buf + ((t + 1) & 1) * (B_ * H1_);
                hw = h1buf + (t & 1) * (B_ * H1_);
            }

            // ---- MAIN: dynamic chunks
            constexpr int NC = ISL0 ? 8 : 12;
            #pragma unroll
            for (int c = 0; c < NC; ++c) {
                int cid;
                const __hip_bfloat16* src;
                int st;
                if (ISL0) {
                    cid = 16 + w * 8 + c;
                    src = a1 + (cid * 32 - S0) + kgrp * 8;
                    st  = ST1;
                } else {
                    cid = w * 12 + c;
                    int k0 = cid * 32;
                    if (k0 < S0) { src = a0 + k0 + kgrp * 8;        st = ST0; }
                    else         { src = a1 + (k0 - S0) + kgrp * 8; st = ST1; }
                }
                bf16x8 bf[NF];
                #pragma unroll
                for (int nf = 0; nf < NF; ++nf)
                    bf[nf] = *reinterpret_cast<const bf16x8*>(
                        wlds + ((size_t)(cid * NF + nf) * 64 + lane) * 8);
                #pragma unroll
                for (int m = 0; m < 4; ++m) {
                    const bf16x8 af = *reinterpret_cast<const bf16x8*>(
                        src + (size_t)(m * 16 + mr) * st);
                    #pragma unroll
                    for (int nf = 0; nf < NF; ++nf)
                        acc[m][nf] = __builtin_amdgcn_mfma_f32_16x16x32_bf16(
                            af, bf[nf], acc[m][nf], 0, 0, 0);
                }
            }

            // ---- dump partials (C layout: row=(lane>>4)*4+r, col=lane&15)
            #pragma unroll
            for (int m = 0; m < 4; ++m)
                #pragma unroll
                for (int nf = 0; nf < NF; ++nf)
                    #pragma unroll
                    for (int r = 0; r < 4; ++r)
                        zp[(w * 64 + m * 16 + kgrp * 4 + r) * ZROW + nf * 16 + mr] =
                            acc[m][nf][r];
            __syncthreads();

            // ---- reduce partials + gates + state update
            const bool msk = mask[b * T_ + t] != 0;
            #pragma unroll
            for (int i = 0; i < UPT; ++i) {
                const int ul = qq * UPT + i;
                float z[4];
                #pragma unroll
                for (int g = 0; g < 4; ++g) {
                    float s = breg[i * 4 + g];
                    #pragma unroll
                    for (int wv = 0; wv < 4; ++wv)
                        s += zp[(wv * 64 + b) * ZROW + g * UPB + ul];
                    z[g] = s;
                }
                float ig = sigmf(z[0]), fg = sigmf(z[1]);
                float gg = tanhf(z[2]), og = sigmf(z[3]);
                float cn = fg * creg[i] + ig * gg;
                float hn = og * tanhf(cn);
                if (msk) { creg[i] = cn; hreg[i] = hn; }
                hw[(size_t)b * HD + ubase + ul] = __float2bfloat16(hreg[i]);
                if (!ISL0) out[((size_t)b * T_ + t) * HD + ubase + ul] = hreg[i];
            }
        }

        // ---- publish h(t)
        bar_arrive(bcnt, bflg, p);
    }
}

__global__ __launch_bounds__(256, 1)
void lstm_persistent(const __hip_bfloat16* __restrict__ xbf,
    const float* __restrict__ W0, const float* __restrict__ U0, const float* __restrict__ b0,
    const float* __restrict__ W1, const float* __restrict__ U1, const float* __restrict__ b1,
    const unsigned char* __restrict__ mask,
    __hip_bfloat16* h0buf, __hip_bfloat16* h1buf, float* __restrict__ out,
    int* bcnt, int* bflg)
{
    __shared__ __align__(16) unsigned char smem[LDS_BYTES];
    const int bid = blockIdx.x;
    if (bid < NL0) {
        run_layer<true, 512, 512, 1024, 2, 1024, 8, 2>(
            smem, W0, U0, b0, xbf, h0buf, h1buf, mask, nullptr, bid * 8, bcnt, bflg);
    } else {
        run_layer<false, 1024, 1024, 512, 1, 512, 4, 1>(
            smem, W1, U1, b1, xbf, h0buf, h1buf, mask, out, (bid - NL0) * 4, bcnt, bflg);
    }
}

// ---------------------------------------------------------------------------
extern "C" void kernel_launch(void* const* d_in, const int* in_sizes, int n_in,
                              void* d_out, int out_size, void* d_ws, size_t ws_size,
                              hipStream_t stream)
{
    const float* inputs = (const float*)d_in[0];
    const float* W0     = (const float*)d_in[1];
    const float* U0     = (const float*)d_in[2];
    const float* b0     = (const float*)d_in[3];
    const float* W1     = (const float*)d_in[4];
    const float* U1     = (const float*)d_in[5];
    const float* b1     = (const float*)d_in[6];
    float* out = (float*)d_out;

    // ws layout: xbf [T][B][D] bf16, h0buf[2][B][H0] bf16, h1buf[2][B][H1] bf16,
    //            mask [B*T] u8, barrier {cnt, flg}
    __hip_bfloat16* xbf   = (__hip_bfloat16*)d_ws;
    __hip_bfloat16* h0buf = xbf + (size_t)T_ * B_ * D_;
    __hip_bfloat16* h1buf = h0buf + 2 * B_ * H0_;
    unsigned char*  mask  = (unsigned char*)(h1buf + 2 * B_ * H1_);
    int* bar = (int*)(mask + B_ * T_);   // 8 bytes, 4-aligned

    hipMemsetAsync(h0buf, 0, (size_t)(2 * B_ * H0_ + 2 * B_ * H1_) * sizeof(__hip_bfloat16), stream);
    hipMemsetAsync(bar, 0, 2 * sizeof(int), stream);
    mask_kernel<<<(B_ * T_) / 4, 256, 0, stream>>>(inputs, mask);
    xbf_kernel<<<(B_ * T_ * D_ / 8) / 256, 256, 0, stream>>>(inputs, xbf);

    const __hip_bfloat16* xbf_c = xbf;
    const unsigned char* mask_c = mask;
    int* bcnt = bar;
    int* bflg = bar + 1;
    void* args[] = {
        (void*)&xbf_c, (void*)&W0, (void*)&U0, (void*)&b0,
        (void*)&W1, (void*)&U1, (void*)&b1,
        (void*)&mask_c, (void*)&h0buf, (void*)&h1buf, (void*)&out,
        (void*)&bcnt, (void*)&bflg
    };
    hipLaunchCooperativeKernel((void*)lstm_persistent, dim3(NBLK), dim3(256),
                               args, 0, stream);
}

// Round 4
// 9319.401 us; speedup vs baseline: 12.0315x; 1.5415x over previous
//
#include <hip/hip_runtime.h>
#include <hip/hip_bf16.h>
#include <cstdint>
#include <cstddef>

#define B_   64
#define T_   512
#define D_   512
#define H0_  1024
#define H1_  512
#define NBLK 256
#define NL0  128

typedef __attribute__((ext_vector_type(8))) short bf16x8;
typedef __attribute__((ext_vector_type(4))) float f32x4;

#define LDS_BYTES 135168     // 96KB weight frags + 36KB padded z-partials
#define ZP_OFF    98304

__device__ __forceinline__ float sigmf(float x) { return 1.0f / (1.0f + __expf(-x)); }

// ---------------------------------------------------------------------------
// Flag-array grid barrier: no serialized atomic chain.
// arrive: one release fence (wbl2) + relaxed store to own flag (parallel).
// wait:   wave 0 polls 256 flags with relaxed loads (no per-poll inv),
//         one acquire fence (inv) after exit, then syncthreads.
// ---------------------------------------------------------------------------
__device__ __forceinline__ void bar_wait(int* flags, int p) {
    if (p > 0) {
        if (threadIdx.x < 64) {
            const int l = threadIdx.x;
            for (;;) {
                int a = __hip_atomic_load(flags + l,       __ATOMIC_RELAXED, __HIP_MEMORY_SCOPE_AGENT);
                int b = __hip_atomic_load(flags + l + 64,  __ATOMIC_RELAXED, __HIP_MEMORY_SCOPE_AGENT);
                int c = __hip_atomic_load(flags + l + 128, __ATOMIC_RELAXED, __HIP_MEMORY_SCOPE_AGENT);
                int d = __hip_atomic_load(flags + l + 192, __ATOMIC_RELAXED, __HIP_MEMORY_SCOPE_AGENT);
                if (__all((a >= p) && (b >= p) && (c >= p) && (d >= p))) break;
                __builtin_amdgcn_s_sleep(4);
            }
            // one inv for the whole block (CU L1 + XCD L2 are shared; R2
            // validated leader-side acquire + syncthreads cross-XCD)
            __builtin_amdgcn_fence(__ATOMIC_ACQUIRE, "agent");
        }
        __syncthreads();
    }
}

__device__ __forceinline__ void bar_arrive(int* flags, int bid, int p) {
    __syncthreads();                 // all waves' stores accepted (vmcnt0)
    if (threadIdx.x == 0) {
        __builtin_amdgcn_fence(__ATOMIC_RELEASE, "agent");   // wbl2: push h to LLC
        __hip_atomic_store(flags + bid, p + 1, __ATOMIC_RELAXED, __HIP_MEMORY_SCOPE_AGENT);
    }
}

// ---------------------------------------------------------------------------
// mask[b,t] = any(inputs[b,t,:] != 0) — one wave per row
// ---------------------------------------------------------------------------
__global__ void mask_kernel(const float* __restrict__ x, unsigned char* __restrict__ mask) {
    int row  = blockIdx.x * 4 + (threadIdx.x >> 6);
    int lane = threadIdx.x & 63;
    const float4* p = reinterpret_cast<const float4*>(x + (size_t)row * D_) + lane * 2;
    float4 a = p[0], b = p[1];
    bool nz = (a.x != 0.f) | (a.y != 0.f) | (a.z != 0.f) | (a.w != 0.f)
            | (b.x != 0.f) | (b.y != 0.f) | (b.z != 0.f) | (b.w != 0.f);
    int m = __any(nz);
    if (lane == 0) mask[row] = m ? 1 : 0;
}

// ---------------------------------------------------------------------------
// inputs [B][T][D] f32 -> xbf [T][B][D] bf16
// ---------------------------------------------------------------------------
__global__ void xbf_kernel(const float* __restrict__ in, __hip_bfloat16* __restrict__ xbf) {
    int i  = blockIdx.x * 256 + threadIdx.x;     // octet index
    int d8 = i & 63;                              // D/8 = 64
    int row = i >> 6;                             // b*T + t
    int b = row >> 9, t = row & 511;
    const float* src = in + (size_t)row * D_ + d8 * 8;
    __hip_bfloat16 o[8];
    #pragma unroll
    for (int j = 0; j < 8; ++j) o[j] = __float2bfloat16(src[j]);
    *reinterpret_cast<bf16x8*>(xbf + ((size_t)t * B_ + b) * D_ + d8 * 8) =
        *reinterpret_cast<bf16x8*>(o);
}

// ---------------------------------------------------------------------------
// Persistent per-layer loop. Block owns UPB hidden units (4*UPB z-columns).
// K=1536 over 4 waves. L0 k-chunk map: wave w gets 4 x-chunks (cid=w*4+c,
// k<512, computed BEFORE the barrier wait) + 8 h-chunks (cid=16+w*8+c).
// L1: contiguous cid=w*12+c (all dynamic).
// ---------------------------------------------------------------------------
template<bool ISL0, int S0, int ST0, int ST1, int NF, int HD, int UPB, int UPT>
__device__ void run_layer(unsigned char* smem,
    const float* __restrict__ W, const float* __restrict__ U, const float* __restrict__ bias,
    const __hip_bfloat16* __restrict__ xbf,
    __hip_bfloat16* h0buf, __hip_bfloat16* h1buf,
    const unsigned char* __restrict__ mask,
    float* __restrict__ out, int ubase, int* flags, int bid)
{
    const int tid = threadIdx.x;
    __hip_bfloat16* wlds = (__hip_bfloat16*)smem;
    float* zp = (float*)(smem + ZP_OFF);
    constexpr int ZROW = (NF == 2) ? 36 : 20;    // 4*ZROW % 32 == 16 -> 2 lanes/bank (free)

    // ---- one-time: fill LDS weight slice, pre-swizzled into MFMA B-fragment order
    for (int e = tid; e < 48 * NF * 64; e += 256) {
        int ln  = e & 63;
        int nf  = (e >> 6) % NF;
        int cid = e / (64 * NF);
        int nn  = nf * 16 + (ln & 15);
        int col = (nn / UPB) * HD + ubase + (nn % UPB);   // gate-major columns
        int kb  = cid * 32 + (ln >> 4) * 8;
        __hip_bfloat16* dst = wlds + ((size_t)(cid * NF + nf) * 64 + ln) * 8;
        #pragma unroll
        for (int j = 0; j < 8; ++j) {
            int k = kb + j;
            float v = (k < S0) ? W[(size_t)k * (4 * HD) + col]
                               : U[(size_t)(k - S0) * (4 * HD) + col];
            dst[j] = __float2bfloat16(v);
        }
    }

    // ---- per-thread recurrent state: batch b = tid>>2, UPT consecutive units
    const int b  = tid >> 2;
    const int qq = tid & 3;
    float hreg[UPT], creg[UPT], breg[UPT * 4];
    #pragma unroll
    for (int i = 0; i < UPT; ++i) {
        hreg[i] = 0.f; creg[i] = 0.f;
        #pragma unroll
        for (int g = 0; g < 4; ++g)
            breg[i * 4 + g] = bias[g * HD + ubase + qq * UPT + i];
    }
    __syncthreads();

    const int w = tid >> 6, lane = tid & 63;
    const int mr = lane & 15, kgrp = lane >> 4;

    #pragma unroll 1
    for (int p = 0; p <= T_; ++p) {
        const int t = ISL0 ? p : (p - 1);
        const bool active = ISL0 ? (p < T_) : (p >= 1);

        f32x4 acc[4][NF];
        if (active) {
            #pragma unroll
            for (int m = 0; m < 4; ++m)
                #pragma unroll
                for (int nf = 0; nf < NF; ++nf) {
                    f32x4 z = {0.f, 0.f, 0.f, 0.f};
                    acc[m][nf] = z;
                }
        }

        // ---- PRE: x-only chunks (L0), independent of the barrier
        if (ISL0 && active) {
            const __hip_bfloat16* a0 = xbf + (size_t)t * B_ * D_;
            #pragma unroll
            for (int c = 0; c < 4; ++c) {
                const int cid = w * 4 + c;
                const __hip_bfloat16* src = a0 + cid * 32 + kgrp * 8;
                bf16x8 bf[NF];
                #pragma unroll
                for (int nf = 0; nf < NF; ++nf)
                    bf[nf] = *reinterpret_cast<const bf16x8*>(
                        wlds + ((size_t)(cid * NF + nf) * 64 + lane) * 8);
                #pragma unroll
                for (int m = 0; m < 4; ++m) {
                    const bf16x8 af = *reinterpret_cast<const bf16x8*>(
                        src + (size_t)(m * 16 + mr) * ST0);
                    #pragma unroll
                    for (int nf = 0; nf < NF; ++nf)
                        acc[m][nf] = __builtin_amdgcn_mfma_f32_16x16x32_bf16(
                            af, bf[nf], acc[m][nf], 0, 0, 0);
                }
            }
        }

        // ---- wait for h(t-1) from all blocks
        bar_wait(flags, p);

        if (active) {
            const __hip_bfloat16* a0;
            const __hip_bfloat16* a1;
            __hip_bfloat16* hw;
            if (ISL0) {
                a0 = nullptr;  // x handled in PRE
                a1 = h0buf + ((t + 1) & 1) * (B_ * H0_);
                hw = h0buf + (t & 1) * (B_ * H0_);
            } else {
                a0 = h0buf + (t & 1) * (B_ * H0_);
                a1 = h1buf + ((t + 1) & 1) * (B_ * H1_);
                hw = h1buf + (t & 1) * (B_ * H1_);
            }

            // ---- MAIN: dynamic chunks
            constexpr int NC = ISL0 ? 8 : 12;
            #pragma unroll
            for (int c = 0; c < NC; ++c) {
                int cid;
                const __hip_bfloat16* src;
                int st;
                if (ISL0) {
                    cid = 16 + w * 8 + c;
                    src = a1 + (cid * 32 - S0) + kgrp * 8;
                    st  = ST1;
                } else {
                    cid = w * 12 + c;
                    int k0 = cid * 32;
                    if (k0 < S0) { src = a0 + k0 + kgrp * 8;        st = ST0; }
                    else         { src = a1 + (k0 - S0) + kgrp * 8; st = ST1; }
                }
                bf16x8 bf[NF];
                #pragma unroll
                for (int nf = 0; nf < NF; ++nf)
                    bf[nf] = *reinterpret_cast<const bf16x8*>(
                        wlds + ((size_t)(cid * NF + nf) * 64 + lane) * 8);
                #pragma unroll
                for (int m = 0; m < 4; ++m) {
                    const bf16x8 af = *reinterpret_cast<const bf16x8*>(
                        src + (size_t)(m * 16 + mr) * st);
                    #pragma unroll
                    for (int nf = 0; nf < NF; ++nf)
                        acc[m][nf] = __builtin_amdgcn_mfma_f32_16x16x32_bf16(
                            af, bf[nf], acc[m][nf], 0, 0, 0);
                }
            }

            // ---- dump partials (C layout: row=(lane>>4)*4+r, col=lane&15)
            #pragma unroll
            for (int m = 0; m < 4; ++m)
                #pragma unroll
                for (int nf = 0; nf < NF; ++nf)
                    #pragma unroll
                    for (int r = 0; r < 4; ++r)
                        zp[(w * 64 + m * 16 + kgrp * 4 + r) * ZROW + nf * 16 + mr] =
                            acc[m][nf][r];
            __syncthreads();

            // ---- reduce partials + gates + state update
            const bool msk = mask[b * T_ + t] != 0;
            #pragma unroll
            for (int i = 0; i < UPT; ++i) {
                const int ul = qq * UPT + i;
                float z[4];
                #pragma unroll
                for (int g = 0; g < 4; ++g) {
                    float s = breg[i * 4 + g];
                    #pragma unroll
                    for (int wv = 0; wv < 4; ++wv)
                        s += zp[(wv * 64 + b) * ZROW + g * UPB + ul];
                    z[g] = s;
                }
                float ig = sigmf(z[0]), fg = sigmf(z[1]);
                float gg = tanhf(z[2]), og = sigmf(z[3]);
                float cn = fg * creg[i] + ig * gg;
                float hn = og * tanhf(cn);
                if (msk) { creg[i] = cn; hreg[i] = hn; }
                hw[(size_t)b * HD + ubase + ul] = __float2bfloat16(hreg[i]);
                if (!ISL0) out[((size_t)b * T_ + t) * HD + ubase + ul] = hreg[i];
            }
        }

        // ---- publish h(t)
        bar_arrive(flags, bid, p);
    }
}

__global__ __launch_bounds__(256, 1)
void lstm_persistent(const __hip_bfloat16* __restrict__ xbf,
    const float* __restrict__ W0, const float* __restrict__ U0, const float* __restrict__ b0,
    const float* __restrict__ W1, const float* __restrict__ U1, const float* __restrict__ b1,
    const unsigned char* __restrict__ mask,
    __hip_bfloat16* h0buf, __hip_bfloat16* h1buf, float* __restrict__ out,
    int* flags)
{
    __shared__ __align__(16) unsigned char smem[LDS_BYTES];
    const int bid = blockIdx.x;
    if (bid < NL0) {
        run_layer<true, 512, 512, 1024, 2, 1024, 8, 2>(
            smem, W0, U0, b0, xbf, h0buf, h1buf, mask, nullptr, bid * 8, flags, bid);
    } else {
        run_layer<false, 1024, 1024, 512, 1, 512, 4, 1>(
            smem, W1, U1, b1, xbf, h0buf, h1buf, mask, out, (bid - NL0) * 4, flags, bid);
    }
}

// ---------------------------------------------------------------------------
extern "C" void kernel_launch(void* const* d_in, const int* in_sizes, int n_in,
                              void* d_out, int out_size, void* d_ws, size_t ws_size,
                              hipStream_t stream)
{
    const float* inputs = (const float*)d_in[0];
    const float* W0     = (const float*)d_in[1];
    const float* U0     = (const float*)d_in[2];
    const float* b0     = (const float*)d_in[3];
    const float* W1     = (const float*)d_in[4];
    const float* U1     = (const float*)d_in[5];
    const float* b1     = (const float*)d_in[6];
    float* out = (float*)d_out;

    // ws layout: xbf [T][B][D] bf16, h0buf[2][B][H0] bf16, h1buf[2][B][H1] bf16,
    //            mask [B*T] u8, flags [NBLK] int
    __hip_bfloat16* xbf   = (__hip_bfloat16*)d_ws;
    __hip_bfloat16* h0buf = xbf + (size_t)T_ * B_ * D_;
    __hip_bfloat16* h1buf = h0buf + 2 * B_ * H0_;
    unsigned char*  mask  = (unsigned char*)(h1buf + 2 * B_ * H1_);
    int* flags = (int*)(mask + B_ * T_);   // 4-aligned

    hipMemsetAsync(h0buf, 0, (size_t)(2 * B_ * H0_ + 2 * B_ * H1_) * sizeof(__hip_bfloat16), stream);
    hipMemsetAsync(flags, 0, NBLK * sizeof(int), stream);
    mask_kernel<<<(B_ * T_) / 4, 256, 0, stream>>>(inputs, mask);
    xbf_kernel<<<(B_ * T_ * D_ / 8) / 256, 256, 0, stream>>>(inputs, xbf);

    const __hip_bfloat16* xbf_c = xbf;
    const unsigned char* mask_c = mask;
    void* args[] = {
        (void*)&xbf_c, (void*)&W0, (void*)&U0, (void*)&b0,
        (void*)&W1, (void*)&U1, (void*)&b1,
        (void*)&mask_c, (void*)&h0buf, (void*)&h1buf, (void*)&out,
        (void*)&flags
    };
    hipLaunchCooperativeKernel((void*)lstm_persistent, dim3(NBLK), dim3(256),
                               args, 0, stream);
}

// Round 5
// 7801.495 us; speedup vs baseline: 14.3725x; 1.1946x over previous
//
#include <hip/hip_runtime.h>
#include <hip/hip_bf16.h>
#include <cstdint>
#include <cstddef>

#define B_   64
#define T_   512
#define D_   512
#define H0_  1024
#define H1_  512
#define NBLK 256
#define NL0  128

typedef __attribute__((ext_vector_type(8))) short bf16x8;
typedef __attribute__((ext_vector_type(4))) float f32x4;
typedef unsigned long long u64;

#define LDS_BYTES 135168     // 96KB weight frags + 36KB padded z-partials
#define ZP_OFF    98304

__device__ __forceinline__ float sigmf(float x) { return 1.0f / (1.0f + __expf(-x)); }

__device__ __forceinline__ unsigned short bf16bits(float x) {
    union { __hip_bfloat16 h; unsigned short s; } u;
    u.h = __float2bfloat16(x);
    return u.s;
}

// ---------------------------------------------------------------------------
// Fence-free grid barrier. All h data moves through LLC (sc0 sc1 atomics),
// so no L2 writeback/invalidate is ever needed.
// arrive: syncthreads (vmcnt0: stores acked at LLC) + relaxed store to own flag.
// wait:   wave 0 spins on all 256 flags with relaxed 8B loads, syncthreads.
// ---------------------------------------------------------------------------
__device__ __forceinline__ void bar_wait(const int* flags, int p) {
    if (p > 0) {
        if (threadIdx.x < 64) {
            const u64* f = (const u64*)flags;
            const int l = threadIdx.x;
            for (;;) {
                u64 a = __hip_atomic_load((u64*)(f + l),      __ATOMIC_RELAXED, __HIP_MEMORY_SCOPE_AGENT);
                u64 b = __hip_atomic_load((u64*)(f + 64 + l), __ATOMIC_RELAXED, __HIP_MEMORY_SCOPE_AGENT);
                bool ok = ((int)a >= p) && ((int)(a >> 32) >= p) &&
                          ((int)b >= p) && ((int)(b >> 32) >= p);
                if (__all(ok)) break;
                __builtin_amdgcn_s_sleep(4);
            }
        }
        __syncthreads();
    }
}

__device__ __forceinline__ void bar_arrive(int* flags, int bid, int p) {
    __syncthreads();                 // each wave: s_waitcnt vmcnt(0) before s_barrier
    if (threadIdx.x == 0)
        __hip_atomic_store(flags + bid, p + 1, __ATOMIC_RELAXED, __HIP_MEMORY_SCOPE_AGENT);
}

// ---------------------------------------------------------------------------
// mask[b,t] = any(inputs[b,t,:] != 0) — one wave per row
// ---------------------------------------------------------------------------
__global__ void mask_kernel(const float* __restrict__ x, unsigned char* __restrict__ mask) {
    int row  = blockIdx.x * 4 + (threadIdx.x >> 6);
    int lane = threadIdx.x & 63;
    const float4* p = reinterpret_cast<const float4*>(x + (size_t)row * D_) + lane * 2;
    float4 a = p[0], b = p[1];
    bool nz = (a.x != 0.f) | (a.y != 0.f) | (a.z != 0.f) | (a.w != 0.f)
            | (b.x != 0.f) | (b.y != 0.f) | (b.z != 0.f) | (b.w != 0.f);
    int m = __any(nz);
    if (lane == 0) mask[row] = m ? 1 : 0;
}

// ---------------------------------------------------------------------------
// inputs [B][T][D] f32 -> xbf [T][B][D] bf16
// ---------------------------------------------------------------------------
__global__ void xbf_kernel(const float* __restrict__ in, __hip_bfloat16* __restrict__ xbf) {
    int i  = blockIdx.x * 256 + threadIdx.x;     // octet index
    int d8 = i & 63;                              // D/8 = 64
    int row = i >> 6;                             // b*T + t
    int b = row >> 9, t = row & 511;
    const float* src = in + (size_t)row * D_ + d8 * 8;
    __hip_bfloat16 o[8];
    #pragma unroll
    for (int j = 0; j < 8; ++j) o[j] = __float2bfloat16(src[j]);
    *reinterpret_cast<bf16x8*>(xbf + ((size_t)t * B_ + b) * D_ + d8 * 8) =
        *reinterpret_cast<bf16x8*>(o);
}

// ---------------------------------------------------------------------------
// Persistent per-layer loop. Block owns UPB hidden units (4*UPB z-columns).
// K=1536 over 4 waves. L0: wave w owns 4 x-chunks (PRE, before barrier) +
// 8 h-chunks (MAIN). L1: 12 chunks, all MAIN.
// MAIN A-loads are agent-scope relaxed atomics (LLC-direct), 4-chunk pipelined.
// ---------------------------------------------------------------------------
template<bool ISL0, int S0, int ST0, int ST1, int NF, int HD, int UPB>
__device__ void run_layer(unsigned char* smem,
    const float* __restrict__ W, const float* __restrict__ U, const float* __restrict__ bias,
    const __hip_bfloat16* __restrict__ xbf,
    __hip_bfloat16* h0buf, __hip_bfloat16* h1buf,
    const unsigned char* __restrict__ mask,
    float* __restrict__ out, int ubase, int* flags, int bid)
{
    const int tid = threadIdx.x;
    __hip_bfloat16* wlds = (__hip_bfloat16*)smem;
    float* zp = (float*)(smem + ZP_OFF);
    constexpr int ZROW = (NF == 2) ? 36 : 20;    // 4*ZROW % 32 == 16 -> 2 lanes/bank (free)
    constexpr int ACTQ = UPB / 2;                // threads (qq) active in gate phase

    // ---- one-time: fill LDS weight slice, pre-swizzled into MFMA B-fragment order
    for (int e = tid; e < 48 * NF * 64; e += 256) {
        int ln  = e & 63;
        int nf  = (e >> 6) % NF;
        int cid = e / (64 * NF);
        int nn  = nf * 16 + (ln & 15);
        int col = (nn / UPB) * HD + ubase + (nn % UPB);   // gate-major columns
        int kb  = cid * 32 + (ln >> 4) * 8;
        __hip_bfloat16* dst = wlds + ((size_t)(cid * NF + nf) * 64 + ln) * 8;
        #pragma unroll
        for (int j = 0; j < 8; ++j) {
            int k = kb + j;
            float v = (k < S0) ? W[(size_t)k * (4 * HD) + col]
                               : U[(size_t)(k - S0) * (4 * HD) + col];
            dst[j] = __float2bfloat16(v);
        }
    }

    // ---- per-thread recurrent state: batch b = tid>>2, 2 consecutive units
    const int b  = tid >> 2;
    const int qq = tid & 3;
    float hreg[2] = {0.f, 0.f}, creg[2] = {0.f, 0.f}, breg[8];
    if (qq < ACTQ) {
        #pragma unroll
        for (int i = 0; i < 2; ++i)
            #pragma unroll
            for (int g = 0; g < 4; ++g)
                breg[i * 4 + g] = bias[g * HD + ubase + qq * 2 + i];
    }
    __syncthreads();

    const int w = tid >> 6, lane = tid & 63;
    const int mr = lane & 15, kgrp = lane >> 4;

    #pragma unroll 1
    for (int p = 0; p <= T_; ++p) {
        const int t = ISL0 ? p : (p - 1);
        const bool active = ISL0 ? (p < T_) : (p >= 1);

        f32x4 acc[4][NF];
        if (active) {
            #pragma unroll
            for (int m = 0; m < 4; ++m)
                #pragma unroll
                for (int nf = 0; nf < NF; ++nf) {
                    f32x4 z = {0.f, 0.f, 0.f, 0.f};
                    acc[m][nf] = z;
                }
        }

        // ---- PRE: x-only chunks (L0), independent of the barrier (plain, L2-warm)
        if (ISL0 && active) {
            const __hip_bfloat16* a0 = xbf + (size_t)t * B_ * D_;
            #pragma unroll
            for (int c = 0; c < 4; ++c) {
                const int cid = w * 4 + c;
                const __hip_bfloat16* src = a0 + cid * 32 + kgrp * 8;
                bf16x8 bf[NF];
                #pragma unroll
                for (int nf = 0; nf < NF; ++nf)
                    bf[nf] = *reinterpret_cast<const bf16x8*>(
                        wlds + ((size_t)(cid * NF + nf) * 64 + lane) * 8);
                #pragma unroll
                for (int m = 0; m < 4; ++m) {
                    const bf16x8 af = *reinterpret_cast<const bf16x8*>(
                        src + (size_t)(m * 16 + mr) * ST0);
                    #pragma unroll
                    for (int nf = 0; nf < NF; ++nf)
                        acc[m][nf] = __builtin_amdgcn_mfma_f32_16x16x32_bf16(
                            af, bf[nf], acc[m][nf], 0, 0, 0);
                }
            }
        }

        // ---- wait for h(t-1) from all blocks
        bar_wait(flags, p);

        if (active) {
            const __hip_bfloat16* a0;
            const __hip_bfloat16* a1;
            __hip_bfloat16* hw;
            if (ISL0) {
                a0 = nullptr;  // x handled in PRE
                a1 = h0buf + ((t + 1) & 1) * (B_ * H0_);
                hw = h0buf + (t & 1) * (B_ * H0_);
            } else {
                a0 = h0buf + (t & 1) * (B_ * H0_);
                a1 = h1buf + ((t + 1) & 1) * (B_ * H1_);
                hw = h1buf + (t & 1) * (B_ * H1_);
            }

            // ---- MAIN: h chunks, LLC-direct loads, 4-deep pipeline
            constexpr int NC = ISL0 ? 8 : 12;
            u64 areg[4][8];
            auto ldc = [&](int c, u64* dst) {
                const __hip_bfloat16* src;
                int st;
                if (ISL0) {
                    int cid = 16 + w * 8 + c;
                    src = a1 + (cid * 32 - S0) + kgrp * 8;
                    st  = ST1;
                } else {
                    int cid = w * 12 + c;
                    int k0 = cid * 32;
                    if (k0 < S0) { src = a0 + k0 + kgrp * 8;        st = ST0; }
                    else         { src = a1 + (k0 - S0) + kgrp * 8; st = ST1; }
                }
                #pragma unroll
                for (int m = 0; m < 4; ++m) {
                    u64* hp = (u64*)(src + (size_t)(m * 16 + mr) * st);
                    dst[2 * m]     = __hip_atomic_load(hp,     __ATOMIC_RELAXED, __HIP_MEMORY_SCOPE_AGENT);
                    dst[2 * m + 1] = __hip_atomic_load(hp + 1, __ATOMIC_RELAXED, __HIP_MEMORY_SCOPE_AGENT);
                }
            };
            #pragma unroll
            for (int c = 0; c < 4; ++c) ldc(c, areg[c]);
            #pragma unroll
            for (int c = 0; c < NC; ++c) {
                u64 cur[8];
                #pragma unroll
                for (int j = 0; j < 8; ++j) cur[j] = areg[c & 3][j];
                if (c + 4 < NC) ldc(c + 4, areg[c & 3]);
                const int cid = ISL0 ? (16 + w * 8 + c) : (w * 12 + c);
                bf16x8 bfr[NF];
                #pragma unroll
                for (int nf = 0; nf < NF; ++nf)
                    bfr[nf] = *reinterpret_cast<const bf16x8*>(
                        wlds + ((size_t)(cid * NF + nf) * 64 + lane) * 8);
                #pragma unroll
                for (int m = 0; m < 4; ++m) {
                    union { u64 u[2]; bf16x8 v; } au;
                    au.u[0] = cur[2 * m]; au.u[1] = cur[2 * m + 1];
                    #pragma unroll
                    for (int nf = 0; nf < NF; ++nf)
                        acc[m][nf] = __builtin_amdgcn_mfma_f32_16x16x32_bf16(
                            au.v, bfr[nf], acc[m][nf], 0, 0, 0);
                }
            }

            // ---- dump partials (C layout: row=(lane>>4)*4+r, col=lane&15)
            #pragma unroll
            for (int m = 0; m < 4; ++m)
                #pragma unroll
                for (int nf = 0; nf < NF; ++nf)
                    #pragma unroll
                    for (int r = 0; r < 4; ++r)
                        zp[(w * 64 + m * 16 + kgrp * 4 + r) * ZROW + nf * 16 + mr] =
                            acc[m][nf][r];
            __syncthreads();

            // ---- reduce partials + gates + state update (2 units/thread)
            if (qq < ACTQ) {
                const bool msk = mask[b * T_ + t] != 0;
                #pragma unroll
                for (int i = 0; i < 2; ++i) {
                    const int ul = qq * 2 + i;
                    float z[4];
                    #pragma unroll
                    for (int g = 0; g < 4; ++g) {
                        float s = breg[i * 4 + g];
                        #pragma unroll
                        for (int wv = 0; wv < 4; ++wv)
                            s += zp[(wv * 64 + b) * ZROW + g * UPB + ul];
                        z[g] = s;
                    }
                    float ig = sigmf(z[0]), fg = sigmf(z[1]);
                    float gg = tanhf(z[2]), og = sigmf(z[3]);
                    float cn = fg * creg[i] + ig * gg;
                    float hn = og * tanhf(cn);
                    if (msk) { creg[i] = cn; hreg[i] = hn; }
                }
                union { unsigned short s[2]; unsigned u; } hv;
                hv.s[0] = bf16bits(hreg[0]);
                hv.s[1] = bf16bits(hreg[1]);
                __hip_atomic_store((unsigned*)&hw[(size_t)b * HD + ubase + qq * 2], hv.u,
                                   __ATOMIC_RELAXED, __HIP_MEMORY_SCOPE_AGENT);
                if (!ISL0) {
                    float2 ov; ov.x = hreg[0]; ov.y = hreg[1];
                    *reinterpret_cast<float2*>(&out[((size_t)b * T_ + t) * HD + ubase + qq * 2]) = ov;
                }
            }
        }

        // ---- publish h(t)
        bar_arrive(flags, bid, p);
    }
}

__global__ __launch_bounds__(256, 1)
void lstm_persistent(const __hip_bfloat16* __restrict__ xbf,
    const float* __restrict__ W0, const float* __restrict__ U0, const float* __restrict__ b0,
    const float* __restrict__ W1, const float* __restrict__ U1, const float* __restrict__ b1,
    const unsigned char* __restrict__ mask,
    __hip_bfloat16* h0buf, __hip_bfloat16* h1buf, float* __restrict__ out,
    int* flags)
{
    __shared__ __align__(16) unsigned char smem[LDS_BYTES];
    const int bid = blockIdx.x;
    if (bid < NL0) {
        run_layer<true, 512, 512, 1024, 2, 1024, 8>(
            smem, W0, U0, b0, xbf, h0buf, h1buf, mask, nullptr, bid * 8, flags, bid);
    } else {
        run_layer<false, 1024, 1024, 512, 1, 512, 4>(
            smem, W1, U1, b1, xbf, h0buf, h1buf, mask, out, (bid - NL0) * 4, flags, bid);
    }
}

// ---------------------------------------------------------------------------
extern "C" void kernel_launch(void* const* d_in, const int* in_sizes, int n_in,
                              void* d_out, int out_size, void* d_ws, size_t ws_size,
                              hipStream_t stream)
{
    const float* inputs = (const float*)d_in[0];
    const float* W0     = (const float*)d_in[1];
    const float* U0     = (const float*)d_in[2];
    const float* b0     = (const float*)d_in[3];
    const float* W1     = (const float*)d_in[4];
    const float* U1     = (const float*)d_in[5];
    const float* b1     = (const float*)d_in[6];
    float* out = (float*)d_out;

    // ws layout: xbf [T][B][D] bf16, h0buf[2][B][H0] bf16, h1buf[2][B][H1] bf16,
    //            mask [B*T] u8, flags [NBLK] int
    __hip_bfloat16* xbf   = (__hip_bfloat16*)d_ws;
    __hip_bfloat16* h0buf = xbf + (size_t)T_ * B_ * D_;
    __hip_bfloat16* h1buf = h0buf + 2 * B_ * H0_;
    unsigned char*  mask  = (unsigned char*)(h1buf + 2 * B_ * H1_);
    int* flags = (int*)(mask + B_ * T_);   // 8B-aligned (offset is pow2-multiple)

    hipMemsetAsync(h0buf, 0, (size_t)(2 * B_ * H0_ + 2 * B_ * H1_) * sizeof(__hip_bfloat16), stream);
    hipMemsetAsync(flags, 0, NBLK * sizeof(int), stream);
    mask_kernel<<<(B_ * T_) / 4, 256, 0, stream>>>(inputs, mask);
    xbf_kernel<<<(B_ * T_ * D_ / 8) / 256, 256, 0, stream>>>(inputs, xbf);

    const __hip_bfloat16* xbf_c = xbf;
    const unsigned char* mask_c = mask;
    void* args[] = {
        (void*)&xbf_c, (void*)&W0, (void*)&U0, (void*)&b0,
        (void*)&W1, (void*)&U1, (void*)&b1,
        (void*)&mask_c, (void*)&h0buf, (void*)&h1buf, (void*)&out,
        (void*)&flags
    };
    hipLaunchCooperativeKernel((void*)lstm_persistent, dim3(NBLK), dim3(256),
                               args, 0, stream);
}

// Round 6
// 6469.349 us; speedup vs baseline: 17.3320x; 1.2059x over previous
//
#include <hip/hip_runtime.h>
#include <hip/hip_bf16.h>
#include <cstdint>
#include <cstddef>

#define B_   64
#define T_   512
#define D_   512
#define H0_  1024
#define H1_  512
#define NBLK 256
#define NL0  128
#define NB0  8        // h0 ring depth (decouples L0/L1 WAR by 8 steps)

typedef __attribute__((ext_vector_type(8))) short bf16x8;
typedef __attribute__((ext_vector_type(4))) float f32x4;
typedef unsigned long long u64;

#define LDS_BYTES 135168     // 96KB weight frags + 36KB padded z-partials
#define ZP_OFF    98304

__device__ __forceinline__ float sigmf(float x) { return 1.0f / (1.0f + __expf(-x)); }

__device__ __forceinline__ unsigned short bf16bits(float x) {
    union { __hip_bfloat16 h; unsigned short s; } u;
    u.h = __float2bfloat16(x);
    return u.s;
}

// ---------------------------------------------------------------------------
// Split flag-array barriers (fence-free; all h data is LLC-direct sc0sc1).
// wait128: spin until fl[0..127] >= p (64 lanes, one u64 load each).
// wait_l0: combined fl0[0..127] >= p  AND  fl1[0..127] >= q (WAR slack).
// arrive: syncthreads (vmcnt0 drains h stores at LLC) + relaxed flag store.
// ---------------------------------------------------------------------------
__device__ __forceinline__ void wait128(const int* fl, int p) {
    if (p > 0) {
        if (threadIdx.x < 64) {
            const u64* f = (const u64*)fl + threadIdx.x;
            for (;;) {
                u64 a = __hip_atomic_load((u64*)f, __ATOMIC_RELAXED, __HIP_MEMORY_SCOPE_AGENT);
                if (__all(((int)a >= p) && ((int)(a >> 32) >= p))) break;
                __builtin_amdgcn_s_sleep(2);
            }
        }
        __syncthreads();
    }
}

__device__ __forceinline__ void wait_l0(const int* flags, int p, int q) {
    if (p > 0 || q > 0) {
        if (threadIdx.x < 64) {
            const u64* f0 = (const u64*)flags + threadIdx.x;
            const u64* f1 = (const u64*)(flags + 128) + threadIdx.x;
            for (;;) {
                u64 a = __hip_atomic_load((u64*)f0, __ATOMIC_RELAXED, __HIP_MEMORY_SCOPE_AGENT);
                u64 b = __hip_atomic_load((u64*)f1, __ATOMIC_RELAXED, __HIP_MEMORY_SCOPE_AGENT);
                bool ok = ((int)a >= p) && ((int)(a >> 32) >= p) &&
                          ((int)b >= q) && ((int)(b >> 32) >= q);
                if (__all(ok)) break;
                __builtin_amdgcn_s_sleep(2);
            }
        }
        __syncthreads();
    }
}

__device__ __forceinline__ void arrive(int* slot, int v) {
    __syncthreads();                 // each wave: s_waitcnt vmcnt(0) before s_barrier
    if (threadIdx.x == 0)
        __hip_atomic_store(slot, v, __ATOMIC_RELAXED, __HIP_MEMORY_SCOPE_AGENT);
}

// ---------------------------------------------------------------------------
// mask[b,t] = any(inputs[b,t,:] != 0) — one wave per row
// ---------------------------------------------------------------------------
__global__ void mask_kernel(const float* __restrict__ x, unsigned char* __restrict__ mask) {
    int row  = blockIdx.x * 4 + (threadIdx.x >> 6);
    int lane = threadIdx.x & 63;
    const float4* p = reinterpret_cast<const float4*>(x + (size_t)row * D_) + lane * 2;
    float4 a = p[0], b = p[1];
    bool nz = (a.x != 0.f) | (a.y != 0.f) | (a.z != 0.f) | (a.w != 0.f)
            | (b.x != 0.f) | (b.y != 0.f) | (b.z != 0.f) | (b.w != 0.f);
    int m = __any(nz);
    if (lane == 0) mask[row] = m ? 1 : 0;
}

// ---------------------------------------------------------------------------
// inputs [B][T][D] f32 -> xbf [T][B][D] bf16
// ---------------------------------------------------------------------------
__global__ void xbf_kernel(const float* __restrict__ in, __hip_bfloat16* __restrict__ xbf) {
    int i  = blockIdx.x * 256 + threadIdx.x;     // octet index
    int d8 = i & 63;                              // D/8 = 64
    int row = i >> 6;                             // b*T + t
    int b = row >> 9, t = row & 511;
    const float* src = in + (size_t)row * D_ + d8 * 8;
    __hip_bfloat16 o[8];
    #pragma unroll
    for (int j = 0; j < 8; ++j) o[j] = __float2bfloat16(src[j]);
    *reinterpret_cast<bf16x8*>(xbf + ((size_t)t * B_ + b) * D_ + d8 * 8) =
        *reinterpret_cast<bf16x8*>(o);
}

// ---------------------------------------------------------------------------
// Shared helpers (weight fill, zp dump, gates) expressed inline in each layer
// function to keep all indices compile-time.
// ---------------------------------------------------------------------------
template<int NF, int HD, int UPB, int S0>
__device__ __forceinline__ void fill_weights(__hip_bfloat16* wlds, int tid,
    const float* __restrict__ W, const float* __restrict__ U, int ubase)
{
    for (int e = tid; e < 48 * NF * 64; e += 256) {
        int ln  = e & 63;
        int nf  = (e >> 6) % NF;
        int cid = e / (64 * NF);
        int nn  = nf * 16 + (ln & 15);
        int col = (nn / UPB) * HD + ubase + (nn % UPB);   // gate-major columns
        int kb  = cid * 32 + (ln >> 4) * 8;
        __hip_bfloat16* dst = wlds + ((size_t)(cid * NF + nf) * 64 + ln) * 8;
        #pragma unroll
        for (int j = 0; j < 8; ++j) {
            int k = kb + j;
            float v = (k < S0) ? W[(size_t)k * (4 * HD) + col]
                               : U[(size_t)(k - S0) * (4 * HD) + col];
            dst[j] = __float2bfloat16(v);
        }
    }
}

// ---------------------------------------------------------------------------
// Layer 0: block owns 8 hidden units. Wave w: 4 x-chunks (PRE, cid=w*4+c),
// 8 h0-chunks (MAIN, cid=16+w*8+c). Self-syncs on flagsL0; WAR slack vs L1.
// ---------------------------------------------------------------------------
__device__ void run_l0(unsigned char* smem,
    const float* __restrict__ W, const float* __restrict__ U, const float* __restrict__ bias,
    const __hip_bfloat16* __restrict__ xbf, __hip_bfloat16* h0ring,
    const unsigned char* __restrict__ mask, int ubase, int* flags, int bid)
{
    constexpr int NF = 2, HD = H0_, UPB = 8, ZROW = 36;
    const int tid = threadIdx.x;
    __hip_bfloat16* wlds = (__hip_bfloat16*)smem;
    float* zp = (float*)(smem + ZP_OFF);

    fill_weights<NF, HD, UPB, 512>(wlds, tid, W, U, ubase);

    const int b  = tid >> 2;
    const int qq = tid & 3;
    float hreg[2] = {0.f, 0.f}, creg[2] = {0.f, 0.f}, breg[8];
    #pragma unroll
    for (int i = 0; i < 2; ++i)
        #pragma unroll
        for (int g = 0; g < 4; ++g)
            breg[i * 4 + g] = bias[g * HD + ubase + qq * 2 + i];
    __syncthreads();

    const int w = tid >> 6, lane = tid & 63;
    const int mr = lane & 15, kgrp = lane >> 4;

    #pragma unroll 1
    for (int t = 0; t < T_; ++t) {
        f32x4 acc[4][NF];
        #pragma unroll
        for (int m = 0; m < 4; ++m)
            #pragma unroll
            for (int nf = 0; nf < NF; ++nf) {
                f32x4 z = {0.f, 0.f, 0.f, 0.f};
                acc[m][nf] = z;
            }

        // ---- PRE: x chunks (plain loads, L2-warm), independent of any flag
        {
            const __hip_bfloat16* a0 = xbf + (size_t)t * B_ * D_;
            #pragma unroll
            for (int c = 0; c < 4; ++c) {
                const int cid = w * 4 + c;
                const __hip_bfloat16* src = a0 + cid * 32 + kgrp * 8;
                bf16x8 bf[NF];
                #pragma unroll
                for (int nf = 0; nf < NF; ++nf)
                    bf[nf] = *reinterpret_cast<const bf16x8*>(
                        wlds + ((size_t)(cid * NF + nf) * 64 + lane) * 8);
                #pragma unroll
                for (int m = 0; m < 4; ++m) {
                    const bf16x8 af = *reinterpret_cast<const bf16x8*>(
                        src + (size_t)(m * 16 + mr) * D_);
                    #pragma unroll
                    for (int nf = 0; nf < NF; ++nf)
                        acc[m][nf] = __builtin_amdgcn_mfma_f32_16x16x32_bf16(
                            af, bf[nf], acc[m][nf], 0, 0, 0);
                }
            }
        }

        // ---- wait: h0(t-1) ready (self) + L1 done reading h0(t-8) (WAR)
        wait_l0(flags, t, t - (NB0 - 1));

        // ---- MAIN: 8 h0 chunks, LLC-direct, 4-deep pipeline
        {
            const __hip_bfloat16* hr = h0ring + (size_t)((t + NB0 - 1) % NB0) * (B_ * H0_);
            u64 areg[4][8];
            auto ldc = [&](int c, u64* dst) {
                const int cid = 16 + w * 8 + c;
                const __hip_bfloat16* src = hr + (cid * 32 - 512) + kgrp * 8;
                #pragma unroll
                for (int m = 0; m < 4; ++m) {
                    u64* hp = (u64*)(src + (size_t)(m * 16 + mr) * H0_);
                    dst[2 * m]     = __hip_atomic_load(hp,     __ATOMIC_RELAXED, __HIP_MEMORY_SCOPE_AGENT);
                    dst[2 * m + 1] = __hip_atomic_load(hp + 1, __ATOMIC_RELAXED, __HIP_MEMORY_SCOPE_AGENT);
                }
            };
            #pragma unroll
            for (int c = 0; c < 4; ++c) ldc(c, areg[c]);
            #pragma unroll
            for (int c = 0; c < 8; ++c) {
                u64 cur[8];
                #pragma unroll
                for (int j = 0; j < 8; ++j) cur[j] = areg[c & 3][j];
                if (c + 4 < 8) ldc(c + 4, areg[c & 3]);
                const int cid = 16 + w * 8 + c;
                bf16x8 bfr[NF];
                #pragma unroll
                for (int nf = 0; nf < NF; ++nf)
                    bfr[nf] = *reinterpret_cast<const bf16x8*>(
                        wlds + ((size_t)(cid * NF + nf) * 64 + lane) * 8);
                #pragma unroll
                for (int m = 0; m < 4; ++m) {
                    union { u64 u[2]; bf16x8 v; } au;
                    au.u[0] = cur[2 * m]; au.u[1] = cur[2 * m + 1];
                    #pragma unroll
                    for (int nf = 0; nf < NF; ++nf)
                        acc[m][nf] = __builtin_amdgcn_mfma_f32_16x16x32_bf16(
                            au.v, bfr[nf], acc[m][nf], 0, 0, 0);
                }
            }
        }

        // ---- dump partials
        #pragma unroll
        for (int m = 0; m < 4; ++m)
            #pragma unroll
            for (int nf = 0; nf < NF; ++nf)
                #pragma unroll
                for (int r = 0; r < 4; ++r)
                    zp[(w * 64 + m * 16 + kgrp * 4 + r) * ZROW + nf * 16 + mr] =
                        acc[m][nf][r];
        __syncthreads();

        // ---- gates + state update (all 4 qq active, 2 units each)
        {
            __hip_bfloat16* hw = h0ring + (size_t)(t % NB0) * (B_ * H0_);
            const bool msk = mask[b * T_ + t] != 0;
            #pragma unroll
            for (int i = 0; i < 2; ++i) {
                const int ul = qq * 2 + i;
                float z[4];
                #pragma unroll
                for (int g = 0; g < 4; ++g) {
                    float s = breg[i * 4 + g];
                    #pragma unroll
                    for (int wv = 0; wv < 4; ++wv)
                        s += zp[(wv * 64 + b) * ZROW + g * UPB + ul];
                    z[g] = s;
                }
                float ig = sigmf(z[0]), fg = sigmf(z[1]);
                float gg = tanhf(z[2]), og = sigmf(z[3]);
                float cn = fg * creg[i] + ig * gg;
                float hn = og * tanhf(cn);
                if (msk) { creg[i] = cn; hreg[i] = hn; }
            }
            union { unsigned short s[2]; unsigned u; } hv;
            hv.s[0] = bf16bits(hreg[0]);
            hv.s[1] = bf16bits(hreg[1]);
            __hip_atomic_store((unsigned*)&hw[(size_t)b * HD + ubase + qq * 2], hv.u,
                               __ATOMIC_RELAXED, __HIP_MEMORY_SCOPE_AGENT);
        }

        arrive(flags + bid, t + 1);
    }
}

// ---------------------------------------------------------------------------
// Layer 1: block owns 4 hidden units. Wave w: 8 h0-chunks (cid=w*8+c, done
// before the pacing wait) + 4 h1-chunks (cid=32+w*4+c, after flagsL1 wait).
// ---------------------------------------------------------------------------
__device__ void run_l1(unsigned char* smem,
    const float* __restrict__ W, const float* __restrict__ U, const float* __restrict__ bias,
    const __hip_bfloat16* __restrict__ h0ring, __hip_bfloat16* h1buf,
    const unsigned char* __restrict__ mask, float* __restrict__ out,
    int ubase, int* flags, int bid)
{
    constexpr int NF = 1, HD = H1_, UPB = 4, ZROW = 20;
    const int tid = threadIdx.x;
    __hip_bfloat16* wlds = (__hip_bfloat16*)smem;
    float* zp = (float*)(smem + ZP_OFF);

    fill_weights<NF, HD, UPB, 1024>(wlds, tid, W, U, ubase);

    const int b  = tid >> 2;
    const int qq = tid & 3;
    float hreg[2] = {0.f, 0.f}, creg[2] = {0.f, 0.f}, breg[8];
    if (qq < 2) {
        #pragma unroll
        for (int i = 0; i < 2; ++i)
            #pragma unroll
            for (int g = 0; g < 4; ++g)
                breg[i * 4 + g] = bias[g * HD + ubase + qq * 2 + i];
    }
    __syncthreads();

    const int w = tid >> 6, lane = tid & 63;
    const int mr = lane & 15, kgrp = lane >> 4;

    #pragma unroll 1
    for (int t = 0; t < T_; ++t) {
        f32x4 acc[4][NF];
        #pragma unroll
        for (int m = 0; m < 4; ++m) {
            f32x4 z = {0.f, 0.f, 0.f, 0.f};
            acc[m][0] = z;
        }

        // ---- wait for h0(t) (L0 runs ahead; usually immediate)
        wait128(flags, t + 1);

        // ---- 8 h0 chunks, LLC-direct, 4-deep pipeline
        {
            const __hip_bfloat16* a0 = h0ring + (size_t)(t % NB0) * (B_ * H0_);
            u64 areg[4][8];
            auto ldc = [&](int c, u64* dst) {
                const int cid = w * 8 + c;
                const __hip_bfloat16* src = a0 + cid * 32 + kgrp * 8;
                #pragma unroll
                for (int m = 0; m < 4; ++m) {
                    u64* hp = (u64*)(src + (size_t)(m * 16 + mr) * H0_);
                    dst[2 * m]     = __hip_atomic_load(hp,     __ATOMIC_RELAXED, __HIP_MEMORY_SCOPE_AGENT);
                    dst[2 * m + 1] = __hip_atomic_load(hp + 1, __ATOMIC_RELAXED, __HIP_MEMORY_SCOPE_AGENT);
                }
            };
            #pragma unroll
            for (int c = 0; c < 4; ++c) ldc(c, areg[c]);
            #pragma unroll
            for (int c = 0; c < 8; ++c) {
                u64 cur[8];
                #pragma unroll
                for (int j = 0; j < 8; ++j) cur[j] = areg[c & 3][j];
                if (c + 4 < 8) ldc(c + 4, areg[c & 3]);
                const int cid = w * 8 + c;
                bf16x8 bfr = *reinterpret_cast<const bf16x8*>(
                    wlds + ((size_t)(cid * NF) * 64 + lane) * 8);
                #pragma unroll
                for (int m = 0; m < 4; ++m) {
                    union { u64 u[2]; bf16x8 v; } au;
                    au.u[0] = cur[2 * m]; au.u[1] = cur[2 * m + 1];
                    acc[m][0] = __builtin_amdgcn_mfma_f32_16x16x32_bf16(
                        au.v, bfr, acc[m][0], 0, 0, 0);
                }
            }
        }

        // ---- pacing wait: h1(t-1) from all L1 blocks
        wait128(flags + 128, t);

        // ---- 4 h1 chunks (prefetch all, then compute)
        {
            const __hip_bfloat16* a1 = h1buf + (size_t)((t + 1) & 1) * (B_ * H1_);
            u64 areg[4][8];
            #pragma unroll
            for (int c = 0; c < 4; ++c) {
                const int cid = 32 + w * 4 + c;
                const __hip_bfloat16* src = a1 + (cid - 32) * 32 + kgrp * 8;
                #pragma unroll
                for (int m = 0; m < 4; ++m) {
                    u64* hp = (u64*)(src + (size_t)(m * 16 + mr) * H1_);
                    areg[c][2 * m]     = __hip_atomic_load(hp,     __ATOMIC_RELAXED, __HIP_MEMORY_SCOPE_AGENT);
                    areg[c][2 * m + 1] = __hip_atomic_load(hp + 1, __ATOMIC_RELAXED, __HIP_MEMORY_SCOPE_AGENT);
                }
            }
            #pragma unroll
            for (int c = 0; c < 4; ++c) {
                const int cid = 32 + w * 4 + c;
                bf16x8 bfr = *reinterpret_cast<const bf16x8*>(
                    wlds + ((size_t)(cid * NF) * 64 + lane) * 8);
                #pragma unroll
                for (int m = 0; m < 4; ++m) {
                    union { u64 u[2]; bf16x8 v; } au;
                    au.u[0] = areg[c][2 * m]; au.u[1] = areg[c][2 * m + 1];
                    acc[m][0] = __builtin_amdgcn_mfma_f32_16x16x32_bf16(
                        au.v, bfr, acc[m][0], 0, 0, 0);
                }
            }
        }

        // ---- dump partials
        #pragma unroll
        for (int m = 0; m < 4; ++m)
            #pragma unroll
            for (int r = 0; r < 4; ++r)
                zp[(w * 64 + m * 16 + kgrp * 4 + r) * ZROW + mr] = acc[m][0][r];
        __syncthreads();

        // ---- gates + state update (qq<2 active, 2 units each)
        if (qq < 2) {
            __hip_bfloat16* hw = h1buf + (size_t)(t & 1) * (B_ * H1_);
            const bool msk = mask[b * T_ + t] != 0;
            #pragma unroll
            for (int i = 0; i < 2; ++i) {
                const int ul = qq * 2 + i;
                float z[4];
                #pragma unroll
                for (int g = 0; g < 4; ++g) {
                    float s = breg[i * 4 + g];
                    #pragma unroll
                    for (int wv = 0; wv < 4; ++wv)
                        s += zp[(wv * 64 + b) * ZROW + g * UPB + ul];
                    z[g] = s;
                }
                float ig = sigmf(z[0]), fg = sigmf(z[1]);
                float gg = tanhf(z[2]), og = sigmf(z[3]);
                float cn = fg * creg[i] + ig * gg;
                float hn = og * tanhf(cn);
                if (msk) { creg[i] = cn; hreg[i] = hn; }
            }
            union { unsigned short s[2]; unsigned u; } hv;
            hv.s[0] = bf16bits(hreg[0]);
            hv.s[1] = bf16bits(hreg[1]);
            __hip_atomic_store((unsigned*)&hw[(size_t)b * HD + ubase + qq * 2], hv.u,
                               __ATOMIC_RELAXED, __HIP_MEMORY_SCOPE_AGENT);
            float2 ov; ov.x = hreg[0]; ov.y = hreg[1];
            *reinterpret_cast<float2*>(&out[((size_t)b * T_ + t) * HD + ubase + qq * 2]) = ov;
        }

        arrive(flags + 128 + bid, t + 1);
    }
}

__global__ __launch_bounds__(256, 1)
void lstm_persistent(const __hip_bfloat16* __restrict__ xbf,
    const float* __restrict__ W0, const float* __restrict__ U0, const float* __restrict__ b0,
    const float* __restrict__ W1, const float* __restrict__ U1, const float* __restrict__ b1,
    const unsigned char* __restrict__ mask,
    __hip_bfloat16* h0ring, __hip_bfloat16* h1buf, float* __restrict__ out,
    int* flags)
{
    __shared__ __align__(16) unsigned char smem[LDS_BYTES];
    const int bid = blockIdx.x;
    if (bid < NL0) {
        run_l0(smem, W0, U0, b0, xbf, h0ring, mask, bid * 8, flags, bid);
    } else {
        run_l1(smem, W1, U1, b1, h0ring, h1buf, mask, out, (bid - NL0) * 4, flags, bid - NL0);
    }
}

// ---------------------------------------------------------------------------
extern "C" void kernel_launch(void* const* d_in, const int* in_sizes, int n_in,
                              void* d_out, int out_size, void* d_ws, size_t ws_size,
                              hipStream_t stream)
{
    const float* inputs = (const float*)d_in[0];
    const float* W0     = (const float*)d_in[1];
    const float* U0     = (const float*)d_in[2];
    const float* b0     = (const float*)d_in[3];
    const float* W1     = (const float*)d_in[4];
    const float* U1     = (const float*)d_in[5];
    const float* b1     = (const float*)d_in[6];
    float* out = (float*)d_out;

    // ws layout: xbf [T][B][D] bf16, h0ring[NB0][B][H0] bf16, h1buf[2][B][H1] bf16,
    //            mask [B*T] u8, flags [256] int (L0: 0..127, L1: 128..255)
    __hip_bfloat16* xbf    = (__hip_bfloat16*)d_ws;
    __hip_bfloat16* h0ring = xbf + (size_t)T_ * B_ * D_;
    __hip_bfloat16* h1buf  = h0ring + (size_t)NB0 * B_ * H0_;
    unsigned char*  mask   = (unsigned char*)(h1buf + 2 * B_ * H1_);
    int* flags = (int*)(mask + B_ * T_);   // 8B-aligned

    hipMemsetAsync(h0ring, 0,
        ((size_t)NB0 * B_ * H0_ + 2 * B_ * H1_) * sizeof(__hip_bfloat16), stream);
    hipMemsetAsync(flags, 0, NBLK * sizeof(int), stream);
    mask_kernel<<<(B_ * T_) / 4, 256, 0, stream>>>(inputs, mask);
    xbf_kernel<<<(B_ * T_ * D_ / 8) / 256, 256, 0, stream>>>(inputs, xbf);

    const __hip_bfloat16* xbf_c = xbf;
    const unsigned char* mask_c = mask;
    void* args[] = {
        (void*)&xbf_c, (void*)&W0, (void*)&U0, (void*)&b0,
        (void*)&W1, (void*)&U1, (void*)&b1,
        (void*)&mask_c, (void*)&h0ring, (void*)&h1buf, (void*)&out,
        (void*)&flags
    };
    hipLaunchCooperativeKernel((void*)lstm_persistent, dim3(NBLK), dim3(256),
                               args, 0, stream);
}